// Round 6
// baseline (105.886 us; speedup 1.0000x reference)
//
#include <hip/hip_runtime.h>
#include <hip/hip_bf16.h>

#define NVOX 100000
#define CIN 32
#define COUT 32
#define KOFF 27

typedef __attribute__((ext_vector_type(8))) short short8;
typedef __attribute__((ext_vector_type(4))) float float4v;
typedef __attribute__((ext_vector_type(4))) int   int4v;

// fp32 -> bf16 round-to-nearest-even (finite inputs)
__device__ __forceinline__ short f2bf(float x) {
    union { float f; unsigned u; } v; v.f = x;
    unsigned u = v.u;
    u += 0x7FFFu + ((u >> 16) & 1u);
    return (short)(u >> 16);
}

// ---- pre-pass A: features fp32 -> bf16 (+ zero row at index NVOX) ----
__global__ __launch_bounds__(256) void feat_cvt_kernel(
    const float* __restrict__ feat, unsigned short* __restrict__ fbf)
{
    int i = (blockIdx.x * 256 + threadIdx.x) * 4;
    if (i < NVOX * CIN) {
        float4v f = *(const float4v*)(feat + i);
        short s[4] = { f2bf(f.x), f2bf(f.y), f2bf(f.z), f2bf(f.w) };
        *(ulonglong1*)(fbf + i) = *(ulonglong1*)s;
    } else if (i < (NVOX + 1) * CIN) {
        short s[4] = { 0, 0, 0, 0 };               // zero row for masked gathers
        *(ulonglong1*)(fbf + i) = *(ulonglong1*)s;
    }
}

// ---- pre-pass B: weights fp32 -> bf16 in B-fragment order ----
// wfrag[k*128 + t*64 + ln][j] = W[k][ci=(ln>>4)*8+j][co=t*16+(ln&15)]
__global__ __launch_bounds__(256) void wgt_cvt_kernel(
    const float* __restrict__ weight, short8* __restrict__ wfrag)
{
    int g = blockIdx.x * 256 + threadIdx.x;
    if (g >= KOFF * 2 * 64) return;
    int k   = g >> 7;
    int rem = g & 127;
    int t   = rem >> 6;
    int ln  = rem & 63;
    int co  = t * 16 + (ln & 15);
    int cib = (ln >> 4) * 8;
    const float* wp = weight + (k * CIN + cib) * COUT + co;
    short8 b;
#pragma unroll
    for (int j = 0; j < 8; ++j) b[j] = f2bf(wp[j * COUT]);
    wfrag[g] = b;
}

// ---- pre-pass C: fold mask into idx: enc = mask ? idx : NVOX (zero row) ----
__global__ __launch_bounds__(256) void enc_fold_kernel(
    const int* __restrict__ nbr_idx, const int* __restrict__ nbr_mask,
    int* __restrict__ enc)
{
    int i = (blockIdx.x * 256 + threadIdx.x) * 4;  // N*KOFF = 2.7e6, /4 exact
    if (i >= NVOX * KOFF) return;
    int4v id = *(const int4v*)(nbr_idx + i);
    int4v mk = *(const int4v*)(nbr_mask + i);
    int4v e;
    e.x = mk.x ? id.x : NVOX;
    e.y = mk.y ? id.y : NVOX;
    e.z = mk.z ? id.z : NVOX;
    e.w = mk.w ? id.w : NVOX;
    *(int4v*)(enc + i) = e;
}

__global__ __launch_bounds__(1024, 8) void subm_conv_kernel(
    const unsigned short* __restrict__ fbf,   // bf16 features [N+1,32] (ws)
    const short8* __restrict__ wfrag,         // bf16 B-fragments (ws)
    const float* __restrict__ bias,           // fp32 [32]
    const int* __restrict__ enc_g,            // folded idx [N,27] (ws)
    float* __restrict__ out)                  // fp32 [N,32]
{
    __shared__ short8 wlds[KOFF * 2 * 64];

    const int tid  = threadIdx.x;
    const int lane = tid & 63;
    const int wave = tid >> 6;                 // 0..15
    const int m    = lane & 15;
    const int quad = lane >> 4;

    const int v0 = (blockIdx.x * 16 + wave) * 16;  // 16 voxels per wave
    int v = v0 + m;
    if (v > NVOX - 1) v = NVOX - 1;                // clamp loads; stores guarded

    // issue metadata loads first so latency overlaps weight staging + barrier
    const int* ep = enc_g + v * KOFF;
    int enc[KOFF];
#pragma unroll
    for (int k = 0; k < KOFF; ++k) enc[k] = ep[k];

    for (int g = tid; g < KOFF * 2 * 64; g += 1024) wlds[g] = wfrag[g];
    __syncthreads();

    float4v acc0 = {0.f, 0.f, 0.f, 0.f};
    float4v acc1 = {0.f, 0.f, 0.f, 0.f};

    const char* fb = (const char*)fbf;
    const int   boff = quad * 16;              // byte offset of A-frag in row

    // ---- depth-4 rotating gather pipeline, fully unrolled ----
    short8 abuf[4];
#pragma unroll
    for (int k = 0; k < 4; ++k)
        abuf[k] = *(const short8*)(fb + (size_t)enc[k] * 64 + boff);

#pragma unroll
    for (int k = 0; k < KOFF; ++k) {
        const int slot = k & 3;
        short8 a = abuf[slot];
        if (k + 4 < KOFF)
            abuf[slot] = *(const short8*)(fb + (size_t)enc[k + 4] * 64 + boff);

        short8 wb0 = wlds[k * 128 + lane];
        short8 wb1 = wlds[k * 128 + 64 + lane];
        acc0 = __builtin_amdgcn_mfma_f32_16x16x32_bf16(a, wb0, acc0, 0, 0, 0);
        acc1 = __builtin_amdgcn_mfma_f32_16x16x32_bf16(a, wb1, acc1, 0, 0, 0);
    }

    // C/D layout: col (cout) = lane&15, row (voxel within tile) = quad*4 + reg
    const float bs0 = bias[m];
    const float bs1 = bias[16 + m];
#pragma unroll
    for (int r = 0; r < 4; ++r) {
        int vv = v0 + quad * 4 + r;
        if (vv < NVOX) {
            out[(size_t)vv * COUT + m]      = acc0[r] + bs0;
            out[(size_t)vv * COUT + 16 + m] = acc1[r] + bs1;
        }
    }
}

extern "C" void kernel_launch(void* const* d_in, const int* in_sizes, int n_in,
                              void* d_out, int out_size, void* d_ws, size_t ws_size,
                              hipStream_t stream) {
    const float* feat = (const float*)d_in[0];
    const float* wgt  = (const float*)d_in[1];
    const float* bias = (const float*)d_in[2];
    const int*   nidx = (const int*)d_in[3];
    const int*   nmsk = (const int*)d_in[4];
    float*       out  = (float*)d_out;

    unsigned short* fbf   = (unsigned short*)d_ws;                       // (N+1)*32*2 = 6,400,064 B
    short8*         wfrag = (short8*)((char*)d_ws + 6400064);            // 55,296 B
    int*            enc   = (int*)((char*)d_ws + 6400064 + 55296);       // 10,800,000 B

    feat_cvt_kernel<<<((NVOX + 1) * CIN / 4 + 255) / 256, 256, 0, stream>>>(feat, fbf);
    wgt_cvt_kernel<<<(KOFF * 2 * 64 + 255) / 256, 256, 0, stream>>>(wgt, wfrag);
    enc_fold_kernel<<<(NVOX * KOFF / 4 + 255) / 256, 256, 0, stream>>>(nidx, nmsk, enc);

    const int block = 1024;                        // 16 waves * 16 voxels = 256 voxels/block
    const int grid  = (NVOX + 255) / 256;          // 391
    subm_conv_kernel<<<grid, block, 0, stream>>>(fbf, wfrag, bias, enc, out);
}